// Round 16
// baseline (408.333 us; speedup 1.0000x reference)
//
#include <hip/hip_runtime.h>
#include <math.h>

typedef __bf16 bf16x8 __attribute__((ext_vector_type(8)));
typedef float f32x4 __attribute__((ext_vector_type(4)));

#define DDIM 1024
#define HDIM 4096
#define NE 8
#define TT 4096
#define CAP 9216   // 8192 + 8*128 padding headroom

static const size_t OFF_CTRL   = 0;                                      // 256 B (ctrl[8..16] = padded offsets)
static const size_t OFF_ROWMAP = 256;                                    // CAP*4
static const size_t OFF_WROW   = OFF_ROWMAP + (size_t)CAP * 4;           // CAP*4
static const size_t OFF_ROWPOS = OFF_WROW + (size_t)CAP * 4;             // TT*2*4
static const size_t OFF_TOKE   = OFF_ROWPOS + (size_t)TT * 2 * 4;
static const size_t OFF_TOKW   = OFF_TOKE + (size_t)TT * 2 * 4;
static const size_t OFF_XB     = OFF_TOKW + (size_t)TT * 2 * 4;          // TT*D bf16
static const size_t OFF_W1T    = OFF_XB + (size_t)TT * DDIM * 2;         // E*H*D bf16; reused as pout2 after GEMM1
static const size_t OFF_W2T    = OFF_W1T + (size_t)NE * HDIM * DDIM * 2; // E*D*H bf16
static const size_t OFF_H      = OFF_W2T + (size_t)NE * DDIM * HDIM * 2; // CAP*H bf16
static const size_t OFF_PO     = OFF_H + (size_t)CAP * HDIM * 2;         // CAP*D bf16
static const size_t WS_NEED    = OFF_PO + (size_t)CAP * DDIM * 2;

__device__ __forceinline__ unsigned short f2bf(float f) {
  unsigned int u = __builtin_bit_cast(unsigned int, f);
  u = (u + 0x7FFFu + ((u >> 16) & 1u)) >> 16;
  return (unsigned short)u;
}

__device__ __forceinline__ float bf2f(unsigned short s) {
  return __builtin_bit_cast(float, (unsigned int)s << 16);
}

__device__ __forceinline__ void async16(void* lds, const void* g) {
  __builtin_amdgcn_global_load_lds(
      (__attribute__((address_space(1))) void*)g,
      (__attribute__((address_space(3))) void*)lds, 16, 0, 0);
}

__device__ __forceinline__ float gelu_exact(float v) {
  return 0.5f * v * (1.0f + erff(v * 0.70710678118654752f));
}

// ---------------- convT body: fp32 [e][K_][N_] -> bf16 [e][N_][K_], one 64x64 tile ----------------
__device__ __forceinline__ void convT_body(
    const float* __restrict__ src, unsigned short* __restrict__ dst,
    int K_, int N_, int e, int kbt, int nbt, char* smem) {
  unsigned int (*lds32)[33] = (unsigned int(*)[33])smem;
  int kb = kbt << 6, nb = nbt << 6;
  int t = threadIdx.x;
  const float* s = src + (size_t)e * K_ * N_ + (size_t)kb * N_ + nb;
  int n0 = (t & 15) << 2;
#pragma unroll
  for (int i = 0; i < 2; ++i) {
    int k2 = (i << 4) + (t >> 4);
    float4 a = *(const float4*)(s + (size_t)(2 * k2) * N_ + n0);
    float4 b = *(const float4*)(s + (size_t)(2 * k2 + 1) * N_ + n0);
    lds32[n0 + 0][k2] = (unsigned)f2bf(a.x) | ((unsigned)f2bf(b.x) << 16);
    lds32[n0 + 1][k2] = (unsigned)f2bf(a.y) | ((unsigned)f2bf(b.y) << 16);
    lds32[n0 + 2][k2] = (unsigned)f2bf(a.z) | ((unsigned)f2bf(b.z) << 16);
    lds32[n0 + 3][k2] = (unsigned)f2bf(a.w) | ((unsigned)f2bf(b.w) << 16);
  }
  __syncthreads();
  unsigned short* dp = dst + (size_t)e * (size_t)N_ * K_ + (size_t)nb * K_ + kb;
  int n = t >> 2, c = t & 3;
  uint4 v0, v1;
  v0.x = lds32[n][(c << 2) + 0]; v0.y = lds32[n][(c << 2) + 1];
  v0.z = lds32[n][(c << 2) + 2]; v0.w = lds32[n][(c << 2) + 3];
  int c4 = (c + 4) << 2;
  v1.x = lds32[n][c4 + 0]; v1.y = lds32[n][c4 + 1];
  v1.z = lds32[n][c4 + 2]; v1.w = lds32[n][c4 + 3];
  *(uint4*)(dp + (size_t)n * K_ + (c << 3)) = v0;
  *(uint4*)(dp + (size_t)n * K_ + ((c + 4) << 3)) = v1;
}

// ---------------- fat1: router blocks (1 of 9) interleaved with convT(W1) blocks (8 of 9) ----------------
__global__ __launch_bounds__(256) void fat1_k(
    const float* __restrict__ x, const float* __restrict__ Wr, const float* __restrict__ br,
    unsigned short* __restrict__ xb, int* __restrict__ toke, float* __restrict__ tokw,
    const float* __restrict__ W1, unsigned short* __restrict__ W1T) {
  __shared__ __align__(16) char SMEM[8448];
  int b = blockIdx.x;
  int g = b / 9, r = b % 9;
  if (r != 0) {
    int idx = 8 * g + (r - 1);          // [0, 8192)
    int e = idx >> 10, rem = idx & 1023;
    convT_body(W1, W1T, DDIM, HDIM, e, rem >> 6, rem & 63, SMEM);
    return;
  }
  // ---- router block g ----
  int tid = threadIdx.x, lane = tid & 63, wid = tid >> 6;
  int t = g * 4 + wid;
  const float* xr = x + (size_t)t * DDIM;
  float acc[NE];
#pragma unroll
  for (int e = 0; e < NE; ++e) acc[e] = 0.f;
#pragma unroll
  for (int it = 0; it < DDIM / 256; ++it) {
    int d0 = it * 256 + lane * 4;
    float4 xv = *(const float4*)(xr + d0);
    ushort4 xs;
    xs.x = f2bf(xv.x); xs.y = f2bf(xv.y); xs.z = f2bf(xv.z); xs.w = f2bf(xv.w);
    *(ushort4*)(xb + (size_t)t * DDIM + d0) = xs;
    const float4* w0 = (const float4*)(Wr + (size_t)(d0 + 0) * NE);
    const float4* w1 = (const float4*)(Wr + (size_t)(d0 + 1) * NE);
    const float4* w2 = (const float4*)(Wr + (size_t)(d0 + 2) * NE);
    const float4* w3 = (const float4*)(Wr + (size_t)(d0 + 3) * NE);
    float4 a, bb;
    a = w0[0]; bb = w0[1];
    acc[0] += xv.x * a.x; acc[1] += xv.x * a.y; acc[2] += xv.x * a.z; acc[3] += xv.x * a.w;
    acc[4] += xv.x * bb.x; acc[5] += xv.x * bb.y; acc[6] += xv.x * bb.z; acc[7] += xv.x * bb.w;
    a = w1[0]; bb = w1[1];
    acc[0] += xv.y * a.x; acc[1] += xv.y * a.y; acc[2] += xv.y * a.z; acc[3] += xv.y * a.w;
    acc[4] += xv.y * bb.x; acc[5] += xv.y * bb.y; acc[6] += xv.y * bb.z; acc[7] += xv.y * bb.w;
    a = w2[0]; bb = w2[1];
    acc[0] += xv.z * a.x; acc[1] += xv.z * a.y; acc[2] += xv.z * a.z; acc[3] += xv.z * a.w;
    acc[4] += xv.z * bb.x; acc[5] += xv.z * bb.y; acc[6] += xv.z * bb.z; acc[7] += xv.z * bb.w;
    a = w3[0]; bb = w3[1];
    acc[0] += xv.w * a.x; acc[1] += xv.w * a.y; acc[2] += xv.w * a.z; acc[3] += xv.w * a.w;
    acc[4] += xv.w * bb.x; acc[5] += xv.w * bb.y; acc[6] += xv.w * bb.z; acc[7] += xv.w * bb.w;
  }
#pragma unroll
  for (int e = 0; e < NE; ++e) {
#pragma unroll
    for (int s = 32; s > 0; s >>= 1) acc[e] += __shfl_xor(acc[e], s, 64);
  }
  if (lane == 0) {
    float l[NE];
#pragma unroll
    for (int e = 0; e < NE; ++e) l[e] = acc[e] + br[e];
    int i0 = 0; float m0 = l[0];
#pragma unroll
    for (int e = 1; e < NE; ++e) if (l[e] > m0) { m0 = l[e]; i0 = e; }
    int i1 = -1; float m1 = -3.4e38f;
#pragma unroll
    for (int e = 0; e < NE; ++e) if (e != i0 && l[e] > m1) { m1 = l[e]; i1 = e; }
    float e1 = expf(m1 - m0);
    float s = 1.f + e1;
    toke[2 * t] = i0;  toke[2 * t + 1] = i1;
    tokw[2 * t] = 1.f / s;  tokw[2 * t + 1] = e1 / s;
  }
}

// ---------------- deterministic ballot binning + 128-padding: one block, zero atomics ----------------
__global__ __launch_bounds__(1024) void bin_k(
    const int* __restrict__ toke, const float* __restrict__ tokw,
    int* __restrict__ ctrl, int* __restrict__ rowmap,
    float* __restrict__ wrow, int* __restrict__ rowpos) {
  __shared__ int wcnt[16][8];
  __shared__ int wpre[16][8];
  __shared__ int pbase[9];
  __shared__ int ecnt[8];
  __shared__ int ebase[8];
  int tid = threadIdx.x, lane = tid & 63, w = tid >> 6;

  int myCnt = 0;
  for (int c = 0; c < 8; ++c) {
    int e = toke[c * 1024 + tid];
#pragma unroll
    for (int ee = 0; ee < 8; ++ee) {
      unsigned long long m = __ballot(e == ee);
      if (lane == ee) myCnt += (int)__popcll(m);
    }
  }
  if (lane < 8) wcnt[w][lane] = myCnt;
  __syncthreads();
  if (tid == 0) {
    int off = 0;
    for (int e = 0; e < 8; ++e) {
      int s = 0;
      for (int ww = 0; ww < 16; ++ww) s += wcnt[ww][e];
      ecnt[e] = s;
      pbase[e] = off;
      ebase[e] = off;
      ctrl[8 + e] = off;
      off += ((s + 127) >> 7) << 7;
    }
    pbase[8] = off;
    ctrl[16] = off;
  }
  __syncthreads();

  for (int e = 0; e < 8; ++e) {
    int start = pbase[e] + ecnt[e], end = pbase[e + 1];
    for (int r = start + tid; r < end; r += 1024) { rowmap[r] = 0; wrow[r] = 0.f; }
  }

  for (int c = 0; c < 8; ++c) {
    int slot = c * 1024 + tid;
    int e = toke[slot];
    unsigned long long mown = 0;
#pragma unroll
    for (int ee = 0; ee < 8; ++ee) {
      unsigned long long m = __ballot(e == ee);
      if (lane == ee) wcnt[w][ee] = (int)__popcll(m);
      if (e == ee) mown = m;
    }
    __syncthreads();
    if (tid < 128) {
      int ww = tid >> 3, ee = tid & 7;
      int s = 0;
      for (int p = 0; p < ww; ++p) s += wcnt[p][ee];
      wpre[ww][ee] = s;
    }
    __syncthreads();
    int rank = (int)__popcll(mown & ((1ull << lane) - 1ull));
    int r = ebase[e] + wpre[w][e] + rank;
    rowmap[r] = slot >> 1;
    wrow[r] = tokw[slot];
    rowpos[slot] = r;
    __syncthreads();
    if (tid < 8) {
      int s = 0;
      for (int ww = 0; ww < 16; ++ww) s += wcnt[ww][tid];
      ebase[tid] += s;
    }
    __syncthreads();
  }
}

// ---------------- fat2: GEMM1 blocks (even) interleaved with convT(W2) blocks (odd) ----------------
// GEMM1 path = r11/r15 proven body: 128^2 tile, single 32KB buffer, stage->sync->compute->sync,
// LDS-bounce coalesced epilogue, gelu -> bf16 hbuf.
__global__ __launch_bounds__(256, 2) void fat2_k(
    const unsigned short* __restrict__ A, const unsigned short* __restrict__ Bt,
    const int* __restrict__ ctrl, const int* __restrict__ rowmap,
    const float* __restrict__ bias, unsigned short* __restrict__ outb,
    const float* __restrict__ W2, unsigned short* __restrict__ W2T) {
  __shared__ __align__(16) char SMEM[32768];
  int b = blockIdx.x;
  if (b & 1) {
    int c = b >> 1;                      // [0, 8192)
    int e = c >> 10, rem = c & 1023;
    convT_body(W2, W2T, HDIM, DDIM, e, rem >> 4, rem & 15, SMEM);
    return;
  }
  int g = b >> 1;
  int cx = g & 31, ry = (g >> 5) & 31, e = g >> 10;
  unsigned short* Asm = (unsigned short*)SMEM;       // 128x64
  unsigned short* Bsm = (unsigned short*)(SMEM + 16384);
  int off0 = ctrl[8 + e], off1 = ctrl[8 + e + 1];
  int row0 = off0 + (ry << 7);
  if (row0 >= off1) return;
  int col0 = cx << 7;
  int tid = threadIdx.x, lane = tid & 63, wid = tid >> 6;
  int wr = wid >> 1, wc = wid & 1;

  const unsigned short* Asrc[4];
  const unsigned short* Bsrc[4];
#pragma unroll
  for (int c = 0; c < 4; ++c) {
    int ar = row0 + (c << 5) + (tid >> 3);
    Asrc[c] = A + (size_t)rowmap[ar] * DDIM + ((tid & 7) << 3);
    int brw = col0 + (c << 5) + (tid >> 3);
    Bsrc[c] = Bt + ((size_t)e * HDIM + brw) * DDIM + ((tid & 7) << 3);
  }

  f32x4 acc[4][4];
#pragma unroll
  for (int m = 0; m < 4; ++m)
#pragma unroll
    for (int n = 0; n < 4; ++n) acc[m][n] = (f32x4){0.f, 0.f, 0.f, 0.f};

  int arow_rd = ((wr << 6) + (lane & 15)) << 6;
  int brow_rd = ((wc << 6) + (lane & 15)) << 6;
  int koff = (lane >> 4) << 3;

  for (int k0 = 0; k0 < DDIM; k0 += 64) {
#pragma unroll
    for (int c = 0; c < 4; ++c) {
      async16(SMEM + (((c << 8) + (wid << 6)) << 4), Asrc[c] + k0);
      async16(SMEM + 16384 + (((c << 8) + (wid << 6)) << 4), Bsrc[c] + k0);
    }
    __syncthreads();
#pragma unroll
    for (int kk = 0; kk < 64; kk += 32) {
      bf16x8 af[4], bfr[4];
#pragma unroll
      for (int m = 0; m < 4; ++m)
        af[m] = *(const bf16x8*)&Asm[arow_rd + (m << 10) + kk + koff];
#pragma unroll
      for (int n = 0; n < 4; ++n)
        bfr[n] = *(const bf16x8*)&Bsm[brow_rd + (n << 10) + kk + koff];
#pragma unroll
      for (int m = 0; m < 4; ++m)
#pragma unroll
        for (int n = 0; n < 4; ++n)
          acc[m][n] = __builtin_amdgcn_mfma_f32_16x16x32_bf16(af[m], bfr[n], acc[m][n], 0, 0, 0);
    }
    __syncthreads();
  }

  unsigned short (*Cl)[128] = (unsigned short(*)[128])SMEM;
  int r_b = (lane >> 4) << 2;
  int c_b = lane & 15;
#pragma unroll
  for (int n = 0; n < 4; ++n) {
    int col_l = (wc << 6) + (n << 4) + c_b;
    float bv = bias[e * HDIM + col0 + col_l];
#pragma unroll
    for (int m = 0; m < 4; ++m) {
#pragma unroll
      for (int r = 0; r < 4; ++r) {
        int row_l = (wr << 6) + (m << 4) + r_b + r;
        Cl[row_l][col_l] = f2bf(gelu_exact(acc[m][n][r] + bv));
      }
    }
  }
  __syncthreads();
  int rb = tid >> 4, cof = (tid & 15) << 3;
#pragma unroll
  for (int j = 0; j < 8; ++j) {
    int row_l = rb + (j << 4);
    uint4 v = *(const uint4*)&Cl[row_l][cof];
    *(uint4*)&outb[(size_t)(row0 + row_l) * HDIM + col0 + cof] = v;
  }
}

// ---------------- GEMM2: r11 structure, K-split 2, bf16 partials, wrow-premultiply ----------------
template <int KTOT, int NTOT>
__global__ __launch_bounds__(256, 2) void gemm2_k(
    const unsigned short* __restrict__ A, const unsigned short* __restrict__ Bt,
    const int* __restrict__ ctrl, const float* __restrict__ wrow,
    const float* __restrict__ bias,
    unsigned short* __restrict__ out0, unsigned short* __restrict__ out1) {
  __shared__ __align__(16) char SMEM[32768];
  unsigned short* Asm = (unsigned short*)SMEM;
  unsigned short* Bsm = (unsigned short*)(SMEM + 16384);
  int zz = blockIdx.z;
  int e = zz & 7, ks = zz >> 3;
  int off0 = ctrl[8 + e], off1 = ctrl[8 + e + 1];
  int row0 = off0 + (blockIdx.y << 7);
  if (row0 >= off1) return;
  int col0 = blockIdx.x << 7;
  int tid = threadIdx.x, lane = tid & 63, wid = tid >> 6;
  int wr = wid >> 1, wc = wid & 1;
  int kbeg = ks * (KTOT / 2);
  int kend = kbeg + (KTOT / 2);
  unsigned short* outp = ks ? out1 : out0;

  const unsigned short* Asrc[4];
  const unsigned short* Bsrc[4];
#pragma unroll
  for (int c = 0; c < 4; ++c) {
    int ar = row0 + (c << 5) + (tid >> 3);
    Asrc[c] = A + (size_t)ar * KTOT + ((tid & 7) << 3);
    int brw = col0 + (c << 5) + (tid >> 3);
    Bsrc[c] = Bt + ((size_t)e * NTOT + brw) * KTOT + ((tid & 7) << 3);
  }

  f32x4 acc[4][4];
#pragma unroll
  for (int m = 0; m < 4; ++m)
#pragma unroll
    for (int n = 0; n < 4; ++n) acc[m][n] = (f32x4){0.f, 0.f, 0.f, 0.f};

  int arow_rd = ((wr << 6) + (lane & 15)) << 6;
  int brow_rd = ((wc << 6) + (lane & 15)) << 6;
  int koff = (lane >> 4) << 3;

  for (int k0 = kbeg; k0 < kend; k0 += 64) {
#pragma unroll
    for (int c = 0; c < 4; ++c) {
      async16(SMEM + (((c << 8) + (wid << 6)) << 4), Asrc[c] + k0);
      async16(SMEM + 16384 + (((c << 8) + (wid << 6)) << 4), Bsrc[c] + k0);
    }
    __syncthreads();
#pragma unroll
    for (int kk = 0; kk < 64; kk += 32) {
      bf16x8 af[4], bfr[4];
#pragma unroll
      for (int m = 0; m < 4; ++m)
        af[m] = *(const bf16x8*)&Asm[arow_rd + (m << 10) + kk + koff];
#pragma unroll
      for (int n = 0; n < 4; ++n)
        bfr[n] = *(const bf16x8*)&Bsm[brow_rd + (n << 10) + kk + koff];
#pragma unroll
      for (int m = 0; m < 4; ++m)
#pragma unroll
        for (int n = 0; n < 4; ++n)
          acc[m][n] = __builtin_amdgcn_mfma_f32_16x16x32_bf16(af[m], bfr[n], acc[m][n], 0, 0, 0);
    }
    __syncthreads();
  }

  unsigned short (*Cl)[128] = (unsigned short(*)[128])SMEM;
  int r_b = (lane >> 4) << 2;
  int c_b = lane & 15;
#pragma unroll
  for (int n = 0; n < 4; ++n) {
    int col_l = (wc << 6) + (n << 4) + c_b;
    float bv = ks ? 0.f : bias[e * NTOT + col0 + col_l];
#pragma unroll
    for (int m = 0; m < 4; ++m) {
#pragma unroll
      for (int r = 0; r < 4; ++r) {
        int row_l = (wr << 6) + (m << 4) + r_b + r;
        Cl[row_l][col_l] = f2bf(wrow[row0 + row_l] * (acc[m][n][r] + bv));
      }
    }
  }
  __syncthreads();
  int rb = tid >> 4, cof = (tid & 15) << 3;
#pragma unroll
  for (int j = 0; j < 8; ++j) {
    int row_l = rb + (j << 4);
    uint4 v = *(const uint4*)&Cl[row_l][cof];
    *(uint4*)&outp[(size_t)(row0 + row_l) * NTOT + col0 + cof] = v;
  }
}

// ---------------- gather: bf16 partials, weights pre-applied ----------------
__global__ __launch_bounds__(256) void gather_k(
    const unsigned short* __restrict__ p0, const unsigned short* __restrict__ p1,
    const int* __restrict__ rowpos, float* __restrict__ out) {
  int t = blockIdx.x, d = threadIdx.x << 2;
  int r0 = rowpos[2 * t], r1 = rowpos[2 * t + 1];
  ushort4 a0 = *(const ushort4*)&p0[(size_t)r0 * DDIM + d];
  ushort4 a1 = *(const ushort4*)&p1[(size_t)r0 * DDIM + d];
  ushort4 b0 = *(const ushort4*)&p0[(size_t)r1 * DDIM + d];
  ushort4 b1 = *(const ushort4*)&p1[(size_t)r1 * DDIM + d];
  float4 o;
  o.x = (bf2f(a0.x) + bf2f(a1.x)) + (bf2f(b0.x) + bf2f(b1.x));
  o.y = (bf2f(a0.y) + bf2f(a1.y)) + (bf2f(b0.y) + bf2f(b1.y));
  o.z = (bf2f(a0.z) + bf2f(a1.z)) + (bf2f(b0.z) + bf2f(b1.z));
  o.w = (bf2f(a0.w) + bf2f(a1.w)) + (bf2f(b0.w) + bf2f(b1.w));
  *(float4*)&out[(size_t)t * DDIM + d] = o;
}

extern "C" void kernel_launch(void* const* d_in, const int* in_sizes, int n_in,
                              void* d_out, int out_size, void* d_ws, size_t ws_size,
                              hipStream_t stream) {
  const float* x  = (const float*)d_in[0];
  const float* W1 = (const float*)d_in[1];
  const float* b1 = (const float*)d_in[2];
  const float* W2 = (const float*)d_in[3];
  const float* b2 = (const float*)d_in[4];
  const float* Wr = (const float*)d_in[5];
  const float* br = (const float*)d_in[6];
  float* out = (float*)d_out;

  if (ws_size < WS_NEED) return;

  char* ws = (char*)d_ws;
  int* ctrl            = (int*)(ws + OFF_CTRL);
  int* rowmap          = (int*)(ws + OFF_ROWMAP);
  float* wrow          = (float*)(ws + OFF_WROW);
  int* rowpos          = (int*)(ws + OFF_ROWPOS);
  int* toke            = (int*)(ws + OFF_TOKE);
  float* tokw          = (float*)(ws + OFF_TOKW);
  unsigned short* xb   = (unsigned short*)(ws + OFF_XB);
  unsigned short* W1T  = (unsigned short*)(ws + OFF_W1T);
  unsigned short* W2T  = (unsigned short*)(ws + OFF_W2T);
  unsigned short* hbuf = (unsigned short*)(ws + OFF_H);
  unsigned short* pout = (unsigned short*)(ws + OFF_PO);
  unsigned short* pout2 = (unsigned short*)(ws + OFF_W1T);  // aliases W1T — dead after GEMM1

  // fat1: router (1024 blocks) || convT(W1) (8192 blocks), 1:8 interleave
  fat1_k<<<9216, 256, 0, stream>>>(x, Wr, br, xb, toke, tokw, W1, W1T);
  bin_k<<<1, 1024, 0, stream>>>(toke, tokw, ctrl, rowmap, wrow, rowpos);

  // fat2: GEMM1 (8192 blocks, even) || convT(W2) (8192 blocks, odd)
  fat2_k<<<16384, 256, 0, stream>>>(xb, W1T, ctrl, rowmap, b1, hbuf, W2, W2T);

  // GEMM2 (K-split 2): pout(+pout2) = bf16(w * (h @ W2[e] + b2))   N=1024, K=2x2048
  gemm2_k<HDIM, DDIM><<<dim3(DDIM / 128, 32, NE * 2), 256, 0, stream>>>(
      hbuf, W2T, ctrl, wrow, b2, pout, pout2);

  gather_k<<<TT, 256, 0, stream>>>(pout, pout2, rowpos, out);
}

// Round 17
// 374.305 us; speedup vs baseline: 1.0909x; 1.0909x over previous
//
#include <hip/hip_runtime.h>
#include <math.h>

typedef __bf16 bf16x8 __attribute__((ext_vector_type(8)));
typedef float f32x4 __attribute__((ext_vector_type(4)));

#define DDIM 1024
#define HDIM 4096
#define NE 8
#define TT 4096
#define CAP 9216   // 8192 + 8*128 padding headroom

static const size_t OFF_CTRL   = 0;                                      // 256 B (ctrl[8..16] = padded offsets)
static const size_t OFF_ROWMAP = 256;                                    // CAP*4
static const size_t OFF_WROW   = OFF_ROWMAP + (size_t)CAP * 4;           // CAP*4
static const size_t OFF_ROWPOS = OFF_WROW + (size_t)CAP * 4;             // TT*2*4
static const size_t OFF_TOKE   = OFF_ROWPOS + (size_t)TT * 2 * 4;
static const size_t OFF_TOKW   = OFF_TOKE + (size_t)TT * 2 * 4;
static const size_t OFF_XB     = OFF_TOKW + (size_t)TT * 2 * 4;          // TT*D bf16
static const size_t OFF_W1T    = OFF_XB + (size_t)TT * DDIM * 2;         // E*H*D bf16; reused as pout2 after GEMM1
static const size_t OFF_W2T    = OFF_W1T + (size_t)NE * HDIM * DDIM * 2; // E*D*H bf16
static const size_t OFF_H      = OFF_W2T + (size_t)NE * DDIM * HDIM * 2; // CAP*H bf16
static const size_t OFF_PO     = OFF_H + (size_t)CAP * HDIM * 2;         // CAP*D bf16
static const size_t WS_NEED    = OFF_PO + (size_t)CAP * DDIM * 2;

__device__ __forceinline__ unsigned short f2bf(float f) {
  unsigned int u = __builtin_bit_cast(unsigned int, f);
  u = (u + 0x7FFFu + ((u >> 16) & 1u)) >> 16;
  return (unsigned short)u;
}

__device__ __forceinline__ float bf2f(unsigned short s) {
  return __builtin_bit_cast(float, (unsigned int)s << 16);
}

__device__ __forceinline__ void async16(void* lds, const void* g) {
  __builtin_amdgcn_global_load_lds(
      (__attribute__((address_space(1))) void*)g,
      (__attribute__((address_space(3))) void*)lds, 16, 0, 0);
}

__device__ __forceinline__ float gelu_exact(float v) {
  return 0.5f * v * (1.0f + erff(v * 0.70710678118654752f));
}

// ---------------- router: logits, top-2, weights; x -> bf16. Vectorized, no atomics. ----------------
__global__ __launch_bounds__(256) void router_k(
    const float* __restrict__ x, const float* __restrict__ Wr, const float* __restrict__ br,
    unsigned short* __restrict__ xb, int* __restrict__ toke, float* __restrict__ tokw) {
  int tid = threadIdx.x, lane = tid & 63, wid = tid >> 6;
  int t = blockIdx.x * 4 + wid;
  const float* xr = x + (size_t)t * DDIM;
  float acc[NE];
#pragma unroll
  for (int e = 0; e < NE; ++e) acc[e] = 0.f;
#pragma unroll
  for (int it = 0; it < DDIM / 256; ++it) {
    int d0 = it * 256 + lane * 4;
    float4 xv = *(const float4*)(xr + d0);
    ushort4 xs;
    xs.x = f2bf(xv.x); xs.y = f2bf(xv.y); xs.z = f2bf(xv.z); xs.w = f2bf(xv.w);
    *(ushort4*)(xb + (size_t)t * DDIM + d0) = xs;
    const float4* w0 = (const float4*)(Wr + (size_t)(d0 + 0) * NE);
    const float4* w1 = (const float4*)(Wr + (size_t)(d0 + 1) * NE);
    const float4* w2 = (const float4*)(Wr + (size_t)(d0 + 2) * NE);
    const float4* w3 = (const float4*)(Wr + (size_t)(d0 + 3) * NE);
    float4 a, b;
    a = w0[0]; b = w0[1];
    acc[0] += xv.x * a.x; acc[1] += xv.x * a.y; acc[2] += xv.x * a.z; acc[3] += xv.x * a.w;
    acc[4] += xv.x * b.x; acc[5] += xv.x * b.y; acc[6] += xv.x * b.z; acc[7] += xv.x * b.w;
    a = w1[0]; b = w1[1];
    acc[0] += xv.y * a.x; acc[1] += xv.y * a.y; acc[2] += xv.y * a.z; acc[3] += xv.y * a.w;
    acc[4] += xv.y * b.x; acc[5] += xv.y * b.y; acc[6] += xv.y * b.z; acc[7] += xv.y * b.w;
    a = w2[0]; b = w2[1];
    acc[0] += xv.z * a.x; acc[1] += xv.z * a.y; acc[2] += xv.z * a.z; acc[3] += xv.z * a.w;
    acc[4] += xv.z * b.x; acc[5] += xv.z * b.y; acc[6] += xv.z * b.z; acc[7] += xv.z * b.w;
    a = w3[0]; b = w3[1];
    acc[0] += xv.w * a.x; acc[1] += xv.w * a.y; acc[2] += xv.w * a.z; acc[3] += xv.w * a.w;
    acc[4] += xv.w * b.x; acc[5] += xv.w * b.y; acc[6] += xv.w * b.z; acc[7] += xv.w * b.w;
  }
#pragma unroll
  for (int e = 0; e < NE; ++e) {
#pragma unroll
    for (int s = 32; s > 0; s >>= 1) acc[e] += __shfl_xor(acc[e], s, 64);
  }
  if (lane == 0) {
    float l[NE];
#pragma unroll
    for (int e = 0; e < NE; ++e) l[e] = acc[e] + br[e];
    int i0 = 0; float m0 = l[0];
#pragma unroll
    for (int e = 1; e < NE; ++e) if (l[e] > m0) { m0 = l[e]; i0 = e; }
    int i1 = -1; float m1 = -3.4e38f;
#pragma unroll
    for (int e = 0; e < NE; ++e) if (e != i0 && l[e] > m1) { m1 = l[e]; i1 = e; }
    float e1 = expf(m1 - m0);
    float s = 1.f + e1;
    toke[2 * t] = i0;  toke[2 * t + 1] = i1;
    tokw[2 * t] = 1.f / s;  tokw[2 * t + 1] = e1 / s;
  }
}

// ---------------- deterministic ballot binning + 128-padding: one block, zero atomics ----------------
__global__ __launch_bounds__(1024) void bin_k(
    const int* __restrict__ toke, const float* __restrict__ tokw,
    int* __restrict__ ctrl, int* __restrict__ rowmap,
    float* __restrict__ wrow, int* __restrict__ rowpos) {
  __shared__ int wcnt[16][8];
  __shared__ int wpre[16][8];
  __shared__ int pbase[9];
  __shared__ int ecnt[8];
  __shared__ int ebase[8];
  int tid = threadIdx.x, lane = tid & 63, w = tid >> 6;

  int myCnt = 0;
  for (int c = 0; c < 8; ++c) {
    int e = toke[c * 1024 + tid];
#pragma unroll
    for (int ee = 0; ee < 8; ++ee) {
      unsigned long long m = __ballot(e == ee);
      if (lane == ee) myCnt += (int)__popcll(m);
    }
  }
  if (lane < 8) wcnt[w][lane] = myCnt;
  __syncthreads();
  if (tid == 0) {
    int off = 0;
    for (int e = 0; e < 8; ++e) {
      int s = 0;
      for (int ww = 0; ww < 16; ++ww) s += wcnt[ww][e];
      ecnt[e] = s;
      pbase[e] = off;
      ebase[e] = off;
      ctrl[8 + e] = off;
      off += ((s + 127) >> 7) << 7;
    }
    pbase[8] = off;
    ctrl[16] = off;
  }
  __syncthreads();

  for (int e = 0; e < 8; ++e) {
    int start = pbase[e] + ecnt[e], end = pbase[e + 1];
    for (int r = start + tid; r < end; r += 1024) { rowmap[r] = 0; wrow[r] = 0.f; }
  }

  for (int c = 0; c < 8; ++c) {
    int slot = c * 1024 + tid;
    int e = toke[slot];
    unsigned long long mown = 0;
#pragma unroll
    for (int ee = 0; ee < 8; ++ee) {
      unsigned long long m = __ballot(e == ee);
      if (lane == ee) wcnt[w][ee] = (int)__popcll(m);
      if (e == ee) mown = m;
    }
    __syncthreads();
    if (tid < 128) {
      int ww = tid >> 3, ee = tid & 7;
      int s = 0;
      for (int p = 0; p < ww; ++p) s += wcnt[p][ee];
      wpre[ww][ee] = s;
    }
    __syncthreads();
    int rank = (int)__popcll(mown & ((1ull << lane) - 1ull));
    int r = ebase[e] + wpre[w][e] + rank;
    rowmap[r] = slot >> 1;
    wrow[r] = tokw[slot];
    rowpos[slot] = r;
    __syncthreads();
    if (tid < 8) {
      int s = 0;
      for (int ww = 0; ww < 16; ++ww) s += wcnt[ww][tid];
      ebase[tid] += s;
    }
    __syncthreads();
  }
}

// ---------------- fp32 -> bf16 transpose convert: src[e][K_][N_] -> dst[e][N_][K_] ----------------
__global__ __launch_bounds__(256) void convT_k(
    const float* __restrict__ src, unsigned short* __restrict__ dst, int K_, int N_) {
  __shared__ unsigned int lds32[64][33];
  int e = blockIdx.z;
  int kb = blockIdx.y << 6, nb = blockIdx.x << 6;
  int t = threadIdx.x;
  const float* s = src + (size_t)e * K_ * N_ + (size_t)kb * N_ + nb;
  int n0 = (t & 15) << 2;
#pragma unroll
  for (int i = 0; i < 2; ++i) {
    int k2 = (i << 4) + (t >> 4);
    float4 a = *(const float4*)(s + (size_t)(2 * k2) * N_ + n0);
    float4 b = *(const float4*)(s + (size_t)(2 * k2 + 1) * N_ + n0);
    lds32[n0 + 0][k2] = (unsigned)f2bf(a.x) | ((unsigned)f2bf(b.x) << 16);
    lds32[n0 + 1][k2] = (unsigned)f2bf(a.y) | ((unsigned)f2bf(b.y) << 16);
    lds32[n0 + 2][k2] = (unsigned)f2bf(a.z) | ((unsigned)f2bf(b.z) << 16);
    lds32[n0 + 3][k2] = (unsigned)f2bf(a.w) | ((unsigned)f2bf(b.w) << 16);
  }
  __syncthreads();
  unsigned short* dp = dst + (size_t)e * (size_t)N_ * K_ + (size_t)nb * K_ + kb;
  int n = t >> 2, c = t & 3;
  uint4 v0, v1;
  v0.x = lds32[n][(c << 2) + 0]; v0.y = lds32[n][(c << 2) + 1];
  v0.z = lds32[n][(c << 2) + 2]; v0.w = lds32[n][(c << 2) + 3];
  int c4 = (c + 4) << 2;
  v1.x = lds32[n][c4 + 0]; v1.y = lds32[n][c4 + 1];
  v1.z = lds32[n][c4 + 2]; v1.w = lds32[n][c4 + 3];
  *(uint4*)(dp + (size_t)n * K_ + (c << 3)) = v0;
  *(uint4*)(dp + (size_t)n * K_ + ((c + 4) << 3)) = v1;
}

// ---------------- grouped expert GEMM: r11 structure (measured optimum) ----------------
template <int KTOT, int NTOT, bool GATHER, bool DOGELU, bool KSPLIT2>
__global__ __launch_bounds__(256, 2) void gemm_k(
    const unsigned short* __restrict__ A, const unsigned short* __restrict__ Bt,
    const int* __restrict__ ctrl, const int* __restrict__ rowmap,
    const float* __restrict__ wrow, const float* __restrict__ bias,
    unsigned short* __restrict__ out0, unsigned short* __restrict__ out1) {
  __shared__ __align__(16) char SMEM[32768];         // K-loop: Asm|Bsm ; epilogue: 128x128 bf16 C-tile
  unsigned short* Asm = (unsigned short*)SMEM;       // 128x64
  unsigned short* Bsm = (unsigned short*)(SMEM + 16384);
  int zz = blockIdx.z;
  int e = KSPLIT2 ? (zz & 7) : zz;
  int ks = KSPLIT2 ? (zz >> 3) : 0;
  int off0 = ctrl[8 + e], off1 = ctrl[8 + e + 1];
  int row0 = off0 + (blockIdx.y << 7);
  if (row0 >= off1) return;
  int col0 = blockIdx.x << 7;
  int tid = threadIdx.x, lane = tid & 63, wid = tid >> 6;
  int wr = wid >> 1, wc = wid & 1;
  int kbeg = KSPLIT2 ? ks * (KTOT / 2) : 0;
  int kend = KSPLIT2 ? kbeg + (KTOT / 2) : KTOT;
  unsigned short* outp = (KSPLIT2 && ks) ? out1 : out0;
  if (DOGELU) outp = out0;

  const unsigned short* Asrc[4];
  const unsigned short* Bsrc[4];
#pragma unroll
  for (int c = 0; c < 4; ++c) {
    int ar = row0 + (c << 5) + (tid >> 3);
    size_t arow = GATHER ? (size_t)rowmap[ar] : (size_t)ar;
    Asrc[c] = A + arow * KTOT + ((tid & 7) << 3);
    int brw = col0 + (c << 5) + (tid >> 3);
    Bsrc[c] = Bt + ((size_t)e * NTOT + brw) * KTOT + ((tid & 7) << 3);
  }

  f32x4 acc[4][4];
#pragma unroll
  for (int m = 0; m < 4; ++m)
#pragma unroll
    for (int n = 0; n < 4; ++n) acc[m][n] = (f32x4){0.f, 0.f, 0.f, 0.f};

  int arow_rd = ((wr << 6) + (lane & 15)) << 6;
  int brow_rd = ((wc << 6) + (lane & 15)) << 6;
  int koff = (lane >> 4) << 3;

  for (int k0 = kbeg; k0 < kend; k0 += 64) {
#pragma unroll
    for (int c = 0; c < 4; ++c) {
      async16(SMEM + (((c << 8) + (wid << 6)) << 4), Asrc[c] + k0);
      async16(SMEM + 16384 + (((c << 8) + (wid << 6)) << 4), Bsrc[c] + k0);
    }
    __syncthreads();
#pragma unroll
    for (int kk = 0; kk < 64; kk += 32) {
      bf16x8 af[4], bfr[4];
#pragma unroll
      for (int m = 0; m < 4; ++m)
        af[m] = *(const bf16x8*)&Asm[arow_rd + (m << 10) + kk + koff];
#pragma unroll
      for (int n = 0; n < 4; ++n)
        bfr[n] = *(const bf16x8*)&Bsm[brow_rd + (n << 10) + kk + koff];
#pragma unroll
      for (int m = 0; m < 4; ++m)
#pragma unroll
        for (int n = 0; n < 4; ++n)
          acc[m][n] = __builtin_amdgcn_mfma_f32_16x16x32_bf16(af[m], bfr[n], acc[m][n], 0, 0, 0);
    }
    __syncthreads();
  }

  // ---- epilogue: fragments -> LDS (bf16) -> coalesced global stores ----
  unsigned short (*Cl)[128] = (unsigned short(*)[128])SMEM;
  int r_b = (lane >> 4) << 2;
  int c_b = lane & 15;
#pragma unroll
  for (int n = 0; n < 4; ++n) {
    int col_l = (wc << 6) + (n << 4) + c_b;
    float bv = (KSPLIT2 && ks) ? 0.f : bias[e * NTOT + col0 + col_l];
#pragma unroll
    for (int m = 0; m < 4; ++m) {
#pragma unroll
      for (int r = 0; r < 4; ++r) {
        int row_l = (wr << 6) + (m << 4) + r_b + r;
        float v = acc[m][n][r] + bv;
        if (DOGELU) {
          Cl[row_l][col_l] = f2bf(gelu_exact(v));
        } else {
          Cl[row_l][col_l] = f2bf(wrow[row0 + row_l] * v);
        }
      }
    }
  }
  __syncthreads();
  int rb = tid >> 4, cof = (tid & 15) << 3;   // 16 rows per pass, 8 bf16 (16B) per lane
#pragma unroll
  for (int j = 0; j < 8; ++j) {
    int row_l = rb + (j << 4);
    uint4 v = *(const uint4*)&Cl[row_l][cof];
    *(uint4*)&outp[(size_t)(row0 + row_l) * NTOT + col0 + cof] = v;
  }
}

// ---------------- gather: bf16 partials, weights pre-applied ----------------
__global__ __launch_bounds__(256) void gather_k(
    const unsigned short* __restrict__ p0, const unsigned short* __restrict__ p1,
    const int* __restrict__ rowpos, float* __restrict__ out) {
  int t = blockIdx.x, d = threadIdx.x << 2;
  int r0 = rowpos[2 * t], r1 = rowpos[2 * t + 1];
  ushort4 a0 = *(const ushort4*)&p0[(size_t)r0 * DDIM + d];
  ushort4 a1 = *(const ushort4*)&p1[(size_t)r0 * DDIM + d];
  ushort4 b0 = *(const ushort4*)&p0[(size_t)r1 * DDIM + d];
  ushort4 b1 = *(const ushort4*)&p1[(size_t)r1 * DDIM + d];
  float4 o;
  o.x = (bf2f(a0.x) + bf2f(a1.x)) + (bf2f(b0.x) + bf2f(b1.x));
  o.y = (bf2f(a0.y) + bf2f(a1.y)) + (bf2f(b0.y) + bf2f(b1.y));
  o.z = (bf2f(a0.z) + bf2f(a1.z)) + (bf2f(b0.z) + bf2f(b1.z));
  o.w = (bf2f(a0.w) + bf2f(a1.w)) + (bf2f(b0.w) + bf2f(b1.w));
  *(float4*)&out[(size_t)t * DDIM + d] = o;
}

extern "C" void kernel_launch(void* const* d_in, const int* in_sizes, int n_in,
                              void* d_out, int out_size, void* d_ws, size_t ws_size,
                              hipStream_t stream) {
  const float* x  = (const float*)d_in[0];
  const float* W1 = (const float*)d_in[1];
  const float* b1 = (const float*)d_in[2];
  const float* W2 = (const float*)d_in[3];
  const float* b2 = (const float*)d_in[4];
  const float* Wr = (const float*)d_in[5];
  const float* br = (const float*)d_in[6];
  float* out = (float*)d_out;

  if (ws_size < WS_NEED) return;

  char* ws = (char*)d_ws;
  int* ctrl            = (int*)(ws + OFF_CTRL);
  int* rowmap          = (int*)(ws + OFF_ROWMAP);
  float* wrow          = (float*)(ws + OFF_WROW);
  int* rowpos          = (int*)(ws + OFF_ROWPOS);
  int* toke            = (int*)(ws + OFF_TOKE);
  float* tokw          = (float*)(ws + OFF_TOKW);
  unsigned short* xb   = (unsigned short*)(ws + OFF_XB);
  unsigned short* W1T  = (unsigned short*)(ws + OFF_W1T);
  unsigned short* W2T  = (unsigned short*)(ws + OFF_W2T);
  unsigned short* hbuf = (unsigned short*)(ws + OFF_H);
  unsigned short* pout = (unsigned short*)(ws + OFF_PO);
  unsigned short* pout2 = (unsigned short*)(ws + OFF_W1T);  // aliases W1T — dead after GEMM1

  router_k<<<TT / 4, 256, 0, stream>>>(x, Wr, br, xb, toke, tokw);
  bin_k<<<1, 1024, 0, stream>>>(toke, tokw, ctrl, rowmap, wrow, rowpos);

  convT_k<<<dim3(HDIM / 64, DDIM / 64, NE), 256, 0, stream>>>(W1, W1T, DDIM, HDIM);
  convT_k<<<dim3(DDIM / 64, HDIM / 64, NE), 256, 0, stream>>>(W2, W2T, HDIM, DDIM);

  // GEMM1: h = gelu(x_rows @ W1[e] + b1)   N=4096, K=1024
  gemm_k<DDIM, HDIM, true, true, false><<<dim3(HDIM / 128, 32, NE), 256, 0, stream>>>(
      xb, W1T, ctrl, rowmap, wrow, b1, hbuf, nullptr);
  // GEMM2 (K-split 2): pout(+pout2) = bf16(w * (h @ W2[e] + b2))   N=1024, K=2x2048
  gemm_k<HDIM, DDIM, false, false, true><<<dim3(DDIM / 128, 32, NE * 2), 256, 0, stream>>>(
      hbuf, W2T, ctrl, rowmap, wrow, b2, pout, pout2);

  gather_k<<<TT, 256, 0, stream>>>(pout, pout2, rowpos, out);
}